// Round 14
// baseline (219.128 us; speedup 1.0000x reference)
//
#include <hip/hip_runtime.h>
#include <hip/hip_bf16.h>

#define NROWS 2048
#define CCH   64
#define FDIM  256
#define CF    16384   // C*F
#define EPSV  1e-3f

typedef __attribute__((ext_vector_type(8))) short  short8;
typedef __attribute__((ext_vector_type(4))) float  f32x4;

__device__ __forceinline__ ushort f2bf(float f) {
  union { float f; unsigned u; } v; v.f = f;
  unsigned r = v.u + 0x7fffu + ((v.u >> 16) & 1u);
  return (ushort)(r >> 16);
}
__device__ __forceinline__ float bf_lo(unsigned u) {
  union { unsigned u; float f; } v; v.u = u << 16; return v.f;
}
__device__ __forceinline__ float bf_hi(unsigned u) {
  union { unsigned u; float f; } v; v.u = u & 0xffff0000u; return v.f;
}
__device__ __forceinline__ unsigned pk2(float a, float b) {
  __hip_bfloat162 h = __float22bfloat162_rn(float2{a, b});
  union { __hip_bfloat162 h; unsigned u; } cv; cv.h = h; return cv.u;
}
__device__ __forceinline__ void gll16(const void* g, void* l) {
  __builtin_amdgcn_global_load_lds(
      (const __attribute__((address_space(1))) unsigned*)g,
      (__attribute__((address_space(3))) unsigned*)l, 16, 0, 0);
}

// ---------------- prep: BN0 stats + x->xt (c,n,f) bf16  ||  w cvt ----------------
// grid 1536: blocks 0..1023 stats_xt (c = b&63, nb = b>>6); blocks 1024.. cvt.
__global__ __launch_bounds__(256) void prep(const float* __restrict__ x,
                                            ushort* __restrict__ xt,
                                            float* __restrict__ ps,
                                            float* __restrict__ pq,
                                            const float* __restrict__ w0,
                                            const float* __restrict__ w1,
                                            ushort* __restrict__ o0,
                                            ushort* __restrict__ o1) {
  __shared__ float red[2][4][64][4];   // 8KB
  const int b = blockIdx.x;
  const int t = threadIdx.x;
  if (b < 1024) {
    const int c  = b & 63;
    const int nb = b >> 6;
    const int cg = t & 63;             // float4 col group
    const int rg = t >> 6;             // 0..3
    const float4* src = (const float4*)x;       // idx = row*4096 + c*64 + cg
    ushort4* dst = (ushort4*)xt;                // idx = c*131072 + row*64 + cg
    float s0 = 0, s1 = 0, s2 = 0, s3 = 0, q0 = 0, q1 = 0, q2 = 0, q3 = 0;
#pragma unroll 8
    for (int i = 0; i < 32; ++i) {
      const int row = nb * 128 + rg * 32 + i;
      float4 v = src[(size_t)row * 4096 + c * 64 + cg];
      s0 += v.x; q0 += v.x * v.x;
      s1 += v.y; q1 += v.y * v.y;
      s2 += v.z; q2 += v.z * v.z;
      s3 += v.w; q3 += v.w * v.w;
      ushort4 u;
      u.x = f2bf(v.x); u.y = f2bf(v.y); u.z = f2bf(v.z); u.w = f2bf(v.w);
      dst[(size_t)c * 131072 + row * 64 + cg] = u;
    }
    red[0][rg][cg][0] = s0; red[0][rg][cg][1] = s1;
    red[0][rg][cg][2] = s2; red[0][rg][cg][3] = s3;
    red[1][rg][cg][0] = q0; red[1][rg][cg][1] = q1;
    red[1][rg][cg][2] = q2; red[1][rg][cg][3] = q3;
    __syncthreads();
    if (t < 128) {
      const int which = t >> 6;        // 0=s, 1=q
      const int g = t & 63;
      float* dstp = which ? pq : ps;
#pragma unroll
      for (int j = 0; j < 4; ++j) {
        float v = red[which][0][g][j] + red[which][1][g][j] +
                  red[which][2][g][j] + red[which][3][g][j];
        dstp[(size_t)nb * CF + c * FDIM + g * 4 + j] = v;
      }
    }
  } else {
    const int n4 = CCH * FDIM * FDIM / 4;
    const size_t stride = (size_t)512 * 256;
    for (size_t i = (size_t)(b - 1024) * 256 + t; i < (size_t)(2 * n4); i += stride) {
      const float* src = (i < (size_t)n4) ? w0 : w1;
      ushort* dst = (i < (size_t)n4) ? o0 : o1;
      size_t j = (i < (size_t)n4) ? i : i - n4;
      float4 v = ((const float4*)src)[j];
      ushort4 u;
      u.x = f2bf(v.x); u.y = f2bf(v.y); u.z = f2bf(v.z); u.w = f2bf(v.w);
      ((ushort4*)dst)[j] = u;
    }
  }
}

// reduce nparts partials -> scale/shift. grid 64 x 256.
__global__ __launch_bounds__(256) void bn_finalize(const float* __restrict__ ps,
                                                   const float* __restrict__ pq,
                                                   int nparts,
                                                   const float* __restrict__ g,
                                                   const float* __restrict__ be,
                                                   float* __restrict__ scale,
                                                   float* __restrict__ shift) {
  int i = blockIdx.x * 256 + threadIdx.x;
  float s = 0, q = 0;
  for (int j = 0; j < nparts; ++j) {
    s += ps[(size_t)j * CF + i];
    q += pq[(size_t)j * CF + i];
  }
  float mean = s * (1.0f / NROWS);
  float var  = q * (1.0f / NROWS) - mean * mean;
  float sc   = g[i] * rsqrtf(var + EPSV);
  scale[i] = sc;
  shift[i] = be[i] - mean * sc;
}

// ---------------- fused batched channel GEMM: 2-tile pipelined blocks ----------------
// Grid 2048 = 64c x 4bn x 8bg. Block: W [64 o][256 k] bf16 = 32KB staged once
// (gll16, XOR-swizzled src+reads); TWO BM=128 tiles (bm = bg*2, bg*2+1).
// t0 burst: all W + tile0 A (16 uint4 = 64 VGPR). One drain. Tile1's A burst
// issues mid-compute (same reg ring, WAR-ordered after tile0 conv). Both acc
// tiles in regs; epilogues deferred so Cs f32[128][64] aliases Ws.
// MODE 0: A=relu(bn0(xt)) -> ybf (c,n,f) + BN1 partials (per-bg).
// MODE 1: A=relu(bn1(ybf)) -> out(n,cf) = xres + acc + bias.
template <int MODE>
__global__ __launch_bounds__(256, 2) void gemm_fused(const ushort* __restrict__ Act,
                                                     const ushort* __restrict__ W,
                                                     const float* __restrict__ bias,
                                                     const float* __restrict__ scale,
                                                     const float* __restrict__ shift,
                                                     const float* __restrict__ xres,
                                                     ushort* __restrict__ Ybf,
                                                     float* __restrict__ outf,
                                                     float* __restrict__ ps1,
                                                     float* __restrict__ pq1) {
  __shared__ __align__(16) ushort Ws[2][64 * 128];    // 32KB; aliased as Cs f32[128][64]
  __shared__ float scl[256], shf[256];                // 2KB
  __shared__ float sstat[2][4][4][16];                // 2KB (MODE0)

  const int t = threadIdx.x;
  const int lane = t & 63, wid = t >> 6;
  const int lm = lane & 15, lg = lane >> 4;

  // bijective XCD swizzle (nwg=2048): XCD j gets wg in [j*256,(j+1)*256) = 8 c's
  const int h  = blockIdx.x;
  const int wg = ((h & 7) << 8) | (h >> 3);
  const int bg = wg & 7, bn = (wg >> 3) & 3, c = wg >> 5;

  // ---- issue ALL W staging now (both halves, 8 gll16/thread) ----
  const int srow = t >> 4;            // 0..15
  const int sb   = (t & 15) * 16;     // 0..240 byte-in-half-row
  const int gsb  = sb ^ ((srow & 7) << 4);
  const char* Wrow = (const char*)(W + ((size_t)c * FDIM + bn * 64) * FDIM);
  char* Ws0 = (char*)&Ws[0][0];
  char* Ws1 = (char*)&Ws[1][0];
#pragma unroll
  for (int i = 0; i < 4; ++i) {
    const int row = i * 16 + srow;   // 0..63
    gll16(Wrow + (size_t)row * 512 + gsb,       Ws0 + row * 256 + sb);
    gll16(Wrow + (size_t)row * 512 + 256 + gsb, Ws1 + row * 256 + sb);
  }

  // ---- issue tile0 A burst: 16 uint4/lane (64 VGPR ring, reused by tile1) ----
  const ushort* Ab0[2];
  const ushort* Ab1[2];
#pragma unroll
  for (int m = 0; m < 2; ++m) {
    Ab0[m] = Act + (size_t)c * (NROWS * FDIM)
                 + (size_t)(bg * 256 + wid * 32 + m * 16 + lm) * FDIM + lg * 8;
    Ab1[m] = Ab0[m] + (size_t)128 * FDIM;
  }
  uint4 ra[8][2];
#pragma unroll
  for (int ks = 0; ks < 8; ++ks)
#pragma unroll
    for (int m = 0; m < 2; ++m)
      ra[ks][m] = *(const uint4*)(Ab0[m] + ks * 32);
  __builtin_amdgcn_sched_barrier(0);

  scl[t] = scale[c * FDIM + t];
  shf[t] = shift[c * FDIM + t];

  float bregs[4];
#pragma unroll
  for (int n = 0; n < 4; ++n)
    bregs[n] = bias[c * FDIM + bn * 64 + n * 16 + lm];

  f32x4 acc0[2][4], acc1[2][4];
#pragma unroll
  for (int m = 0; m < 2; ++m)
#pragma unroll
    for (int n = 0; n < 4; ++n) {
      acc0[m][n] = (f32x4){0.f, 0.f, 0.f, 0.f};
      acc1[m][n] = (f32x4){0.f, 0.f, 0.f, 0.f};
    }

  __syncthreads();   // THE drain: W (both halves) + tile0 A + scl/shf ready

  short8 af[4][2];   // conv output for one half (reused)

#define CONVH(kb)                                                           \
  _Pragma("unroll")                                                         \
  for (int ks = 0; ks < 4; ++ks) {                                          \
    float4 sc0 = *(const float4*)&scl[((kb) + ks) * 32 + lg * 8];           \
    float4 sc1 = *(const float4*)&scl[((kb) + ks) * 32 + lg * 8 + 4];       \
    float4 sh0 = *(const float4*)&shf[((kb) + ks) * 32 + lg * 8];           \
    float4 sh1 = *(const float4*)&shf[((kb) + ks) * 32 + lg * 8 + 4];       \
    _Pragma("unroll")                                                       \
    for (int m = 0; m < 2; ++m) {                                           \
      uint4 u = ra[(kb) + ks][m];                                           \
      float v0 = bf_lo(u.x), v1 = bf_hi(u.x), v2 = bf_lo(u.y), v3 = bf_hi(u.y); \
      float v4 = bf_lo(u.z), v5 = bf_hi(u.z), v6 = bf_lo(u.w), v7 = bf_hi(u.w); \
      v0 = fmaxf(fmaf(v0, sc0.x, sh0.x), 0.f);                              \
      v1 = fmaxf(fmaf(v1, sc0.y, sh0.y), 0.f);                              \
      v2 = fmaxf(fmaf(v2, sc0.z, sh0.z), 0.f);                              \
      v3 = fmaxf(fmaf(v3, sc0.w, sh0.w), 0.f);                              \
      v4 = fmaxf(fmaf(v4, sc1.x, sh1.x), 0.f);                              \
      v5 = fmaxf(fmaf(v5, sc1.y, sh1.y), 0.f);                              \
      v6 = fmaxf(fmaf(v6, sc1.z, sh1.z), 0.f);                              \
      v7 = fmaxf(fmaf(v7, sc1.w, sh1.w), 0.f);                              \
      union { short8 s; unsigned u[4]; } pkd;                               \
      pkd.u[0] = pk2(v0, v1); pkd.u[1] = pk2(v2, v3);                       \
      pkd.u[2] = pk2(v4, v5); pkd.u[3] = pk2(v6, v7);                       \
      af[ks][m] = pkd.s;                                                    \
    }                                                                       \
  }

#define MFMAH(WsH, ACC)                                                     \
  _Pragma("unroll")                                                         \
  for (int ksl = 0; ksl < 4; ++ksl) {                                       \
    short8 bv[4];                                                           \
    _Pragma("unroll")                                                       \
    for (int n = 0; n < 4; ++n) {                                           \
      const int ro = n * 16 + lm;                                           \
      const int byt = (ksl * 64 + lg * 16) ^ ((ro & 7) << 4);               \
      bv[n] = *(const short8*)((WsH) + ro * 256 + byt);                     \
    }                                                                       \
    _Pragma("unroll")                                                       \
    for (int m = 0; m < 2; ++m)                                             \
      _Pragma("unroll")                                                     \
      for (int n = 0; n < 4; ++n)                                           \
        ACC[m][n] = __builtin_amdgcn_mfma_f32_16x16x32_bf16(af[ksl][m],     \
                        bv[n], ACC[m][n], 0, 0, 0);                         \
  }

  // ---- tile 0 ----
  CONVH(0)
  MFMAH(Ws0, acc0)
  CONVH(4)            // ra fully consumed after this
  // issue tile1 A burst mid-compute (WAR on ra orders it after CONVH(4) reads)
#pragma unroll
  for (int ks = 0; ks < 8; ++ks)
#pragma unroll
    for (int m = 0; m < 2; ++m)
      ra[ks][m] = *(const uint4*)(Ab1[m] + ks * 32);
  __builtin_amdgcn_sched_barrier(0);
  MFMAH(Ws1, acc0)

  // ---- tile 1 ----
  CONVH(0)
  MFMAH(Ws0, acc1)
  CONVH(4)
  MFMAH(Ws1, acc1)

  if (MODE == 0) {
    // ---- BN1 column partial stats over both tiles ----
#pragma unroll
    for (int n = 0; n < 4; ++n) {
      float ss = 0, qq = 0;
#pragma unroll
      for (int m = 0; m < 2; ++m)
#pragma unroll
        for (int j = 0; j < 4; ++j) {
          float v0 = acc0[m][n][j] + bregs[n];
          float v1 = acc1[m][n][j] + bregs[n];
          ss += v0 + v1; qq += v0 * v0 + v1 * v1;
        }
      ss += __shfl_xor(ss, 16); ss += __shfl_xor(ss, 32);
      qq += __shfl_xor(qq, 16); qq += __shfl_xor(qq, 32);
      if (lg == 0) {
        sstat[0][wid][n][lm] = ss;
        sstat[1][wid][n][lm] = qq;
      }
    }
  }
  __syncthreads();   // all Ws reads done (+ sstat); Ws reusable as Cs

  // ---- epilogues: two passes over Cs f32[128][64] (aliases Ws) ----
  float* Cs = (float*)&Ws[0][0];
#pragma unroll
  for (int p = 0; p < 2; ++p) {
    const int bm = bg * 2 + p;
#pragma unroll
    for (int m = 0; m < 2; ++m) {
      const int rbase = wid * 32 + m * 16 + lg * 4;
      const int xd = lg << 4;      // == ((rbase>>2)&3)<<4
#pragma unroll
      for (int n = 0; n < 4; ++n) {
        const int col = n * 16 + lm;
#pragma unroll
        for (int j = 0; j < 4; ++j) {
          const float v = (p ? acc1[m][n][j] : acc0[m][n][j]) + bregs[n];
          Cs[(rbase + j) * 64 + (col ^ xd)] = v;
        }
      }
    }
    __syncthreads();

    // coalesced writeout: 8 thr/row, 32 rows/pass, 4 passes
    const int rt = t >> 3;           // 0..31
    const int pcol = (t & 7) * 8;    // 0..56
#pragma unroll
    for (int rb = 0; rb < 4; ++rb) {
      const int row = rb * 32 + rt;
      const int xd = ((row >> 2) & 3) << 4;
      f32x4 v0 = *(const f32x4*)&Cs[row * 64 + (pcol ^ xd)];
      f32x4 v1 = *(const f32x4*)&Cs[row * 64 + ((pcol + 4) ^ xd)];
      if (MODE == 0) {
        const size_t gofs = (size_t)c * (NROWS * FDIM)
                          + (size_t)(bm * 128 + row) * FDIM + bn * 64 + pcol;
        uint4 u;
        u.x = pk2(v0[0], v0[1]); u.y = pk2(v0[2], v0[3]);
        u.z = pk2(v1[0], v1[1]); u.w = pk2(v1[2], v1[3]);
        *(uint4*)(Ybf + gofs) = u;
      } else {
        const size_t gofs = (size_t)(bm * 128 + row) * CF + c * FDIM + bn * 64 + pcol;
        float4 x0 = *(const float4*)(xres + gofs);
        float4 x1 = *(const float4*)(xres + gofs + 4);
        float4 o0, o1;
        o0.x = x0.x + v0[0]; o0.y = x0.y + v0[1]; o0.z = x0.z + v0[2]; o0.w = x0.w + v0[3];
        o1.x = x1.x + v1[0]; o1.y = x1.y + v1[1]; o1.z = x1.z + v1[2]; o1.w = x1.w + v1[3];
        *(float4*)(outf + gofs) = o0;
        *(float4*)(outf + gofs + 4) = o1;
      }
    }
    if (p == 0) __syncthreads();   // before overwriting Cs with tile1
  }

  if (MODE == 0) {
    // ---- partial stats writeout: 128 thr = 2 stats x 4n x 16 cols ----
    if (t < 128) {
      const int stat = t >> 6;
      const int idx = t & 63;
      const int n = idx >> 4, lmm = idx & 15;
      float v = sstat[stat][0][n][lmm] + sstat[stat][1][n][lmm] +
                sstat[stat][2][n][lmm] + sstat[stat][3][n][lmm];
      float* dst = stat ? pq1 : ps1;
      dst[(size_t)bg * CF + c * FDIM + bn * 64 + n * 16 + lmm] = v;
    }
  }
}

// ---------------- launch ----------------
extern "C" void kernel_launch(void* const* d_in, const int* in_sizes, int n_in,
                              void* d_out, int out_size, void* d_ws, size_t ws_size,
                              hipStream_t stream) {
  const float* x   = (const float*)d_in[0];
  const float* w0  = (const float*)d_in[1];
  const float* b0  = (const float*)d_in[2];
  const float* w1  = (const float*)d_in[3];
  const float* b1  = (const float*)d_in[4];
  const float* g0  = (const float*)d_in[5];
  const float* be0 = (const float*)d_in[6];
  const float* g1  = (const float*)d_in[7];
  const float* be1 = (const float*)d_in[8];
  float* out = (float*)d_out;

  char* ws = (char*)d_ws;
  float* ps0    = (float*)ws;                         // 16*CF
  float* pq0    = ps0 + (size_t)16 * CF;              // 16*CF
  float* ps1    = pq0 + (size_t)16 * CF;              // 8*CF used
  float* pq1    = ps1 + (size_t)16 * CF;              // 8*CF used
  float* scale0 = pq1 + (size_t)16 * CF;
  float* shift0 = scale0 + CF;
  float* scale1 = shift0 + CF;
  float* shift1 = scale1 + CF;
  ushort* w0bf = (ushort*)(shift1 + CF);
  ushort* w1bf = w0bf + (size_t)CCH * FDIM * FDIM;
  ushort* xt   = w1bf + (size_t)CCH * FDIM * FDIM;    // (c,n,f) bf16, 67MB
  ushort* ybf  = xt + (size_t)NROWS * CF;             // (c,n,f) bf16, 67MB

  // BN0 stats + x->xt  ||  w0/w1 cvt (one merged kernel)
  prep<<<1536, 256, 0, stream>>>(x, xt, ps0, pq0, w0, w1, w0bf, w1bf);
  bn_finalize<<<64, 256, 0, stream>>>(ps0, pq0, 16, g0, be0, scale0, shift0);

  // linear0 fused: A=relu(bn0(xt)), out ybf (c,n,f) + BN1 partials
  gemm_fused<0><<<2048, 256, 0, stream>>>(
      xt, w0bf, b0, scale0, shift0, nullptr, ybf, nullptr, ps1, pq1);

  bn_finalize<<<64, 256, 0, stream>>>(ps1, pq1, 8, g1, be1, scale1, shift1);

  // linear1 fused: A=relu(bn1(ybf)), out(n,cf) = x + acc + b1
  gemm_fused<1><<<2048, 256, 0, stream>>>(
      ybf, w1bf, b1, scale1, shift1, x, nullptr, out, nullptr, nullptr);
}